// Round 4
// baseline (1132.648 us; speedup 1.0000x reference)
//
#include <hip/hip_runtime.h>
#include <hip/hip_bf16.h>
#include <hip/hip_fp16.h>
#include <math.h>

// Problem constants (fixed by reference)
#define N_NODES 200000
#define FDIM    256     // F
#define MDIM    128     // M
#define KMIX    8       // K mixtures
#define ATTD    128     // ATT
#define NGRAPH  1024
#define TSN     64      // nodes per block

typedef _Float16 half8 __attribute__((ext_vector_type(8)));
typedef _Float16 half4 __attribute__((ext_vector_type(4)));
typedef float    floatx4 __attribute__((ext_vector_type(4)));

// ---------------------------------------------------------------------------
// Kernel 0a: split g (fp32) into fp16 hi/lo packed in MFMA B-fragment order.
// frag idx = (k*8 + ctg)*8 + fc ; per frag 64 lanes x half8.
// B layout (16x16x32 f16): col = lane&15, kdim = (lane>>4)*8 + j.
// ---------------------------------------------------------------------------
__global__ __launch_bounds__(256) void pack_g(
    const float* __restrict__ g, _Float16* __restrict__ gh, _Float16* __restrict__ gl)
{
    int t    = blockIdx.x * 256 + threadIdx.x;   // 0..32767
    int lane = t & 63;
    int frag = t >> 6;         // 0..511
    int fc   = frag & 7;
    int ctg  = (frag >> 3) & 7;
    int k    = frag >> 6;
    int col  = k * 128 + ctg * 16 + (lane & 15);
    int f0   = fc * 32 + (lane >> 4) * 8;
    half8 vh, vl;
    #pragma unroll
    for (int j = 0; j < 8; ++j) {
        float v = g[(size_t)(f0 + j) * 1024 + col];
        _Float16 h = (_Float16)v;
        vh[j] = h;
        vl[j] = (_Float16)(v - (float)h);
    }
    *(half8*)(gh + (size_t)t * 8) = vh;
    *(half8*)(gl + (size_t)t * 8) = vl;
}

// ---------------------------------------------------------------------------
// Kernel 0b: split w1 (fp32 [ATT][M]) into fp16 hi/lo B-fragment order.
// frag idx = ctg*4 + mc (32 frags).
// ---------------------------------------------------------------------------
__global__ __launch_bounds__(256) void pack_w1(
    const float* __restrict__ w1, _Float16* __restrict__ w1h, _Float16* __restrict__ w1l)
{
    int t    = blockIdx.x * 256 + threadIdx.x;   // 0..2047
    int lane = t & 63;
    int frag = t >> 6;         // 0..31
    int mc   = frag & 3;
    int ctg  = frag >> 2;
    int att  = ctg * 16 + (lane & 15);
    int m0   = mc * 32 + (lane >> 4) * 8;
    half8 vh, vl;
    #pragma unroll
    for (int j = 0; j < 8; ++j) {
        float v = w1[att * MDIM + m0 + j];
        _Float16 h = (_Float16)v;
        vh[j] = h;
        vl[j] = (_Float16)(v - (float)h);
    }
    *(half8*)(w1h + (size_t)t * 8) = vh;
    *(half8*)(w1l + (size_t)t * 8) = vl;
}

// ---------------------------------------------------------------------------
// Kernel 1: fused x@g (fp16-split MFMA) -> gaussian -> H -> attention (MFMA)
//   grid: N/64 blocks x 512 threads (8 waves).
//   wave w: n-half = w>>2 (32 nodes, rt=2), col-quarter = w&3 (32 cols, ct=2).
//   fc-loop register double-buffered: frags for (k,fc+1) load before (k,fc)
//   MFMAs issue; the (k+1,0) prefetch overlaps the gaussian epilogue.
// ---------------------------------------------------------------------------
__global__ __launch_bounds__(512, 4) void fused_forward(
    const float* __restrict__ x,
    const _Float16* __restrict__ gh, const _Float16* __restrict__ gl,
    const float* __restrict__ mu, const float* __restrict__ sigma,
    const _Float16* __restrict__ w1h, const _Float16* __restrict__ w1l,
    const float* __restrict__ w2,
    float* __restrict__ Hout, float* __restrict__ scores)
{
    // xs_h/xs_l: [64 nodes][264 f16]  (row stride 528B -> 2-way bank alias, free)
    __shared__ unsigned char smem[64 * 264 * 2 * 2 + 512];   // 68096 B
    _Float16* xs_h = (_Float16*)smem;
    _Float16* xs_l = xs_h + 64 * 264;
    float*    Hs   = (float*)smem;                     // overlay [64][132] f32
    float*    spart = (float*)(smem + 64 * 264 * 2 * 2); // [64][4] att partials

    const int tid   = threadIdx.x;
    const int nBase = blockIdx.x * TSN;

    // ---- stage x tile as fp16 hi/lo ----
    {
        const float4* xg = (const float4*)x;   // 64 float4 per row
        #pragma unroll
        for (int r = 0; r < 8; ++r) {
            int idx  = r * 512 + tid;
            int row  = idx >> 6;       // 0..63
            int quad = idx & 63;       // f-quad
            float4 v = xg[(size_t)(nBase + row) * 64 + quad];
            half4 h, l;
            h[0] = (_Float16)v.x; l[0] = (_Float16)(v.x - (float)h[0]);
            h[1] = (_Float16)v.y; l[1] = (_Float16)(v.y - (float)h[1]);
            h[2] = (_Float16)v.z; l[2] = (_Float16)(v.z - (float)h[2]);
            h[3] = (_Float16)v.w; l[3] = (_Float16)(v.w - (float)h[3]);
            *(half4*)&xs_h[row * 264 + quad * 4] = h;
            *(half4*)&xs_l[row * 264 + quad * 4] = l;
        }
    }
    __syncthreads();

    const int wave  = tid >> 6;
    const int lane  = tid & 63;
    const int c15   = lane & 15;
    const int q     = lane >> 4;
    const int nhalf = wave >> 2;   // 0..1
    const int colq  = wave & 3;    // 0..3

    // B fragment base pointers for this wave's two col-tiles (units: f16)
    // off(k,fc,ct) = k*32768 + (colq*2+ct)*4096 + fc*512 + lane*8
    const _Float16* gh0 = gh + (size_t)(colq * 2) * 4096 + lane * 8;
    const _Float16* gl0 = gl + (size_t)(colq * 2) * 4096 + lane * 8;

    float h[2][2][4];              // [rt][ct][reg] persistent H accumulator
    #pragma unroll
    for (int rt = 0; rt < 2; ++rt)
        #pragma unroll
        for (int ct = 0; ct < 2; ++ct)
            #pragma unroll
            for (int rg = 0; rg < 4; ++rg) h[rt][ct][rg] = 0.f;

    half8 Ah[2][2], Al[2][2], Bh[2][2], Bl[2][2];   // [buf][rt/ct]

#define LOAD_A(buf, fcv)                                                      \
    {                                                                         \
        const int f0_ = (fcv) * 32 + q * 8;                                   \
        _Pragma("unroll")                                                     \
        for (int rt = 0; rt < 2; ++rt) {                                      \
            int node_ = nhalf * 32 + rt * 16 + c15;                           \
            Ah[buf][rt] = *(const half8*)&xs_h[node_ * 264 + f0_];            \
            Al[buf][rt] = *(const half8*)&xs_l[node_ * 264 + f0_];            \
        }                                                                     \
    }
#define LOAD_B(buf, kv, fcv)                                                  \
    {                                                                         \
        size_t o_ = (size_t)(kv) * 32768 + (size_t)(fcv) * 512;               \
        _Pragma("unroll")                                                     \
        for (int ct = 0; ct < 2; ++ct) {                                      \
            Bh[buf][ct] = *(const half8*)(gh0 + o_ + ct * 4096);              \
            Bl[buf][ct] = *(const half8*)(gl0 + o_ + ct * 4096);              \
        }                                                                     \
    }

    LOAD_A(0, 0)
    LOAD_B(0, 0, 0)

    #pragma unroll 1
    for (int k = 0; k < KMIX; ++k) {
        floatx4 acc[2][2];
        #pragma unroll
        for (int rt = 0; rt < 2; ++rt)
            #pragma unroll
            for (int ct = 0; ct < 2; ++ct) acc[rt][ct] = (floatx4)0.f;

        #pragma unroll
        for (int fc = 0; fc < 8; ++fc) {
            const int cur = fc & 1, nxt = cur ^ 1;
            const int nfc = (fc + 1) & 7;
            const int nk  = (fc == 7) ? ((k + 1) & 7) : k;   // wraps harmlessly at end
            LOAD_A(nxt, nfc)
            LOAD_B(nxt, nk, nfc)
            #pragma unroll
            for (int rt = 0; rt < 2; ++rt)
                #pragma unroll
                for (int ct = 0; ct < 2; ++ct) {
                    acc[rt][ct] = __builtin_amdgcn_mfma_f32_16x16x32_f16(Ah[cur][rt], Bh[cur][ct], acc[rt][ct], 0, 0, 0);
                    acc[rt][ct] = __builtin_amdgcn_mfma_f32_16x16x32_f16(Ah[cur][rt], Bl[cur][ct], acc[rt][ct], 0, 0, 0);
                    acc[rt][ct] = __builtin_amdgcn_mfma_f32_16x16x32_f16(Al[cur][rt], Bh[cur][ct], acc[rt][ct], 0, 0, 0);
                }
        }

        // gaussian epilogue: C layout col = lane&15, row = q*4 + reg
        #pragma unroll
        for (int ct = 0; ct < 2; ++ct) {
            int col = k * 128 + colq * 32 + ct * 16 + c15;
            float muv = mu[col];
            float sg  = sigma[col];
            float iv  = 1.0f / (1e-15f + sg * sg);
            #pragma unroll
            for (int rt = 0; rt < 2; ++rt)
                #pragma unroll
                for (int rg = 0; rg < 4; ++rg) {
                    float o = acc[rt][ct][rg];
                    float d = o - muv;
                    h[rt][ct][rg] += o * __expf(-0.5f * d * d * iv);
                }
        }
    }
#undef LOAD_A
#undef LOAD_B

    // ---- H -> LDS overlay ----
    __syncthreads();                   // all xs reads done before Hs overlay
    const int HS_LD = MDIM + 4;
    #pragma unroll
    for (int rt = 0; rt < 2; ++rt)
        #pragma unroll
        for (int ct = 0; ct < 2; ++ct)
            #pragma unroll
            for (int rg = 0; rg < 4; ++rg) {
                int n = nhalf * 32 + rt * 16 + q * 4 + rg;
                int m = colq * 32 + ct * 16 + c15;
                Hs[n * HS_LD + m] = h[rt][ct][rg];
            }
    __syncthreads();

    // ---- vectorized, coalesced H store from LDS ----
    #pragma unroll
    for (int r = 0; r < 4; ++r) {
        int idx  = r * 512 + tid;      // 0..2047
        int node = idx >> 5;           // 0..63
        int mq   = idx & 31;           // float4 column
        float4 v = *(const float4*)&Hs[node * HS_LD + mq * 4];
        *(float4*)&Hout[(size_t)(nBase + node) * MDIM + mq * 4] = v;
    }

    // ---- attention via MFMA: dots = H @ w1^T (fp16 split), same wave tiling
    {
        floatx4 datt[2][2];
        #pragma unroll
        for (int rt = 0; rt < 2; ++rt)
            #pragma unroll
            for (int ct = 0; ct < 2; ++ct) datt[rt][ct] = (floatx4)0.f;

        #pragma unroll
        for (int mc = 0; mc < 4; ++mc) {
            half8 Ahh[2], All[2];
            #pragma unroll
            for (int rt = 0; rt < 2; ++rt) {
                int node = nhalf * 32 + rt * 16 + c15;
                const float* hp = &Hs[node * HS_LD + mc * 32 + q * 8];
                #pragma unroll
                for (int j = 0; j < 8; ++j) {
                    float v = hp[j];
                    _Float16 hi = (_Float16)v;
                    Ahh[rt][j] = hi;
                    All[rt][j] = (_Float16)(v - (float)hi);
                }
            }
            #pragma unroll
            for (int ct = 0; ct < 2; ++ct) {
                int frag = (colq * 2 + ct) * 4 + mc;
                size_t off = ((size_t)frag * 64 + lane) * 8;
                half8 Bhh = *(const half8*)(w1h + off);
                half8 Bll = *(const half8*)(w1l + off);
                #pragma unroll
                for (int rt = 0; rt < 2; ++rt) {
                    datt[rt][ct] = __builtin_amdgcn_mfma_f32_16x16x32_f16(Ahh[rt], Bhh, datt[rt][ct], 0, 0, 0);
                    datt[rt][ct] = __builtin_amdgcn_mfma_f32_16x16x32_f16(Ahh[rt], Bll, datt[rt][ct], 0, 0, 0);
                    datt[rt][ct] = __builtin_amdgcn_mfma_f32_16x16x32_f16(All[rt], Bhh, datt[rt][ct], 0, 0, 0);
                }
            }
        }

        // tanh * w2, reduce over wave's 32 atts -> spart[node][colq]
        float w2v[2];
        #pragma unroll
        for (int ct = 0; ct < 2; ++ct) w2v[ct] = w2[colq * 32 + ct * 16 + c15];

        #pragma unroll
        for (int rt = 0; rt < 2; ++rt) {
            #pragma unroll
            for (int rg = 0; rg < 4; ++rg) {
                float p = 0.f;
                #pragma unroll
                for (int ct = 0; ct < 2; ++ct) {
                    float dot = datt[rt][ct][rg];
                    float e2 = __expf(2.f * dot);      // tanh = 1 - 2/(e^2x+1)
                    float av = 1.f - 2.f / (e2 + 1.f);
                    p = fmaf(av, w2v[ct], p);
                }
                p += __shfl_xor(p, 1);
                p += __shfl_xor(p, 2);
                p += __shfl_xor(p, 4);
                p += __shfl_xor(p, 8);
                if (c15 == 0) {
                    int n = nhalf * 32 + rt * 16 + q * 4 + rg;
                    spart[n * 4 + colq] = p;
                }
            }
        }
    }
    __syncthreads();
    if (tid < 64) {
        const float* sp = &spart[tid * 4];
        scores[nBase + tid] = (sp[0] + sp[1]) + (sp[2] + sp[3]);
    }
}

// ---------------------------------------------------------------------------
// Kernel 2: per-graph segment softmax + weighted pooling.
//   e[i] staged in LDS (exp computed once); float4 pooling, 8-way node par.
// ---------------------------------------------------------------------------
#define CHUNK 1024
__global__ __launch_bounds__(256) void segment_pool(
    const float* __restrict__ H, const float* __restrict__ scores,
    const int* __restrict__ batch, float* __restrict__ out)
{
    const int gidx = blockIdx.x;
    const int tid  = threadIdx.x;

    int lo = 0, hi = N_NODES;
    while (lo < hi) { int mid = (lo + hi) >> 1; if (batch[mid] <  gidx) lo = mid + 1; else hi = mid; }
    const int start = lo;
    hi = N_NODES;
    while (lo < hi) { int mid = (lo + hi) >> 1; if (batch[mid] <= gidx) lo = mid + 1; else hi = mid; }
    const int end = lo;

    __shared__ float red[4];
    __shared__ float ebuf[CHUNK];          // 4KB
    __shared__ float part[8][MDIM];        // 4KB

    // ---- segment max ----
    float mx = -INFINITY;
    for (int i = start + tid; i < end; i += 256) mx = fmaxf(mx, scores[i]);
    #pragma unroll
    for (int o = 32; o > 0; o >>= 1) mx = fmaxf(mx, __shfl_xor(mx, o));
    if ((tid & 63) == 0) red[tid >> 6] = mx;
    __syncthreads();
    mx = fmaxf(fmaxf(red[0], red[1]), fmaxf(red[2], red[3]));

    // ---- chunked: stage e in LDS, pool with float4 ----
    const int mq = tid & 31;               // float4 column 0..31
    const int p  = tid >> 5;               // node-parallel 0..7
    float4 acc = make_float4(0.f, 0.f, 0.f, 0.f);
    float ls = 0.f;                        // local sum of e

    for (int c0 = start; c0 < end; c0 += CHUNK) {
        const int clen = min(end - c0, CHUNK);
        __syncthreads();                   // ebuf reuse from previous chunk
        for (int i = tid; i < clen; i += 256) {
            float e = __expf(scores[c0 + i] - mx);
            ebuf[i] = e;
            ls += e;
        }
        __syncthreads();
        for (int i = p; i < clen; i += 8) {
            float e = ebuf[i];
            const float4 hv = *(const float4*)&H[(size_t)(c0 + i) * MDIM + mq * 4];
            acc.x = fmaf(e, hv.x, acc.x);
            acc.y = fmaf(e, hv.y, acc.y);
            acc.z = fmaf(e, hv.z, acc.z);
            acc.w = fmaf(e, hv.w, acc.w);
        }
    }

    // ---- reduce sum of e ----
    #pragma unroll
    for (int o = 32; o > 0; o >>= 1) ls += __shfl_xor(ls, o);
    if ((tid & 63) == 0) red[tid >> 6] = ls;
    // ---- reduce acc over p via LDS ----
    part[p][mq * 4 + 0] = acc.x;
    part[p][mq * 4 + 1] = acc.y;
    part[p][mq * 4 + 2] = acc.z;
    part[p][mq * 4 + 3] = acc.w;
    __syncthreads();
    if (tid < MDIM) {
        float s = red[0] + red[1] + red[2] + red[3];
        const float inv = 1.f / (s + 1e-16f);
        float a = 0.f;
        #pragma unroll
        for (int pp = 0; pp < 8; ++pp) a += part[pp][tid];
        out[gidx * MDIM + tid] = a * inv;
    }
}

// ---------------------------------------------------------------------------
extern "C" void kernel_launch(void* const* d_in, const int* in_sizes, int n_in,
                              void* d_out, int out_size, void* d_ws, size_t ws_size,
                              hipStream_t stream)
{
    const float* x     = (const float*)d_in[0];
    const float* g     = (const float*)d_in[1];
    const float* mu    = (const float*)d_in[2];
    const float* sigma = (const float*)d_in[3];
    const float* w1    = (const float*)d_in[4];
    const float* w2    = (const float*)d_in[5];
    const int*   batch = (const int*)d_in[6];
    float* out = (float*)d_out;

    // ws: H [N][128] f32 | scores [N] f32 | gh | gl | w1h | w1l
    float*    H      = (float*)d_ws;
    float*    scores = H + (size_t)N_NODES * MDIM;
    _Float16* ghp    = (_Float16*)(scores + N_NODES);
    _Float16* glp    = ghp + (size_t)FDIM * KMIX * MDIM;
    _Float16* w1hp   = glp + (size_t)FDIM * KMIX * MDIM;
    _Float16* w1lp   = w1hp + (size_t)ATTD * MDIM;

    pack_g<<<128, 256, 0, stream>>>(g, ghp, glp);
    pack_w1<<<8, 256, 0, stream>>>(w1, w1hp, w1lp);
    fused_forward<<<N_NODES / TSN, 512, 0, stream>>>(x, ghp, glp, mu, sigma,
                                                     w1hp, w1lp, w2, H, scores);
    segment_pool<<<NGRAPH, 256, 0, stream>>>(H, scores, batch, out);
}

// Round 5
// 679.625 us; speedup vs baseline: 1.6666x; 1.6666x over previous
//
#include <hip/hip_runtime.h>
#include <hip/hip_bf16.h>
#include <hip/hip_fp16.h>
#include <math.h>

// Problem constants (fixed by reference)
#define N_NODES 200000
#define FDIM    256     // F
#define MDIM    128     // M
#define KMIX    8       // K mixtures
#define ATTD    128     // ATT
#define NGRAPH  1024
#define TSN     64      // nodes per block

typedef _Float16 half8 __attribute__((ext_vector_type(8)));
typedef _Float16 half4 __attribute__((ext_vector_type(4)));
typedef float    floatx4 __attribute__((ext_vector_type(4)));

// ---------------------------------------------------------------------------
// Kernel 0: split g AND w1 (fp32) into fp16 hi/lo, packed in MFMA B-frag order.
// Blocks 0..127: g.   frag idx = (k*8 + ctg)*8 + fc ; 64 lanes x half8.
// Blocks 128..135: w1. frag idx = ctg*4 + mc.
// B layout (16x16x32 f16): col = lane&15, kdim = (lane>>4)*8 + j.
// ---------------------------------------------------------------------------
__global__ __launch_bounds__(256) void pack_both(
    const float* __restrict__ g, const float* __restrict__ w1,
    _Float16* __restrict__ gh, _Float16* __restrict__ gl,
    _Float16* __restrict__ w1h, _Float16* __restrict__ w1l)
{
    if (blockIdx.x < 128) {
        int t    = blockIdx.x * 256 + threadIdx.x;   // 0..32767
        int lane = t & 63;
        int frag = t >> 6;         // 0..511
        int fc   = frag & 7;
        int ctg  = (frag >> 3) & 7;
        int k    = frag >> 6;
        int col  = k * 128 + ctg * 16 + (lane & 15);
        int f0   = fc * 32 + (lane >> 4) * 8;
        half8 vh, vl;
        #pragma unroll
        for (int j = 0; j < 8; ++j) {
            float v = g[(size_t)(f0 + j) * 1024 + col];
            _Float16 h = (_Float16)v;
            vh[j] = h;
            vl[j] = (_Float16)(v - (float)h);
        }
        *(half8*)(gh + (size_t)t * 8) = vh;
        *(half8*)(gl + (size_t)t * 8) = vl;
    } else {
        int t    = (blockIdx.x - 128) * 256 + threadIdx.x;   // 0..2047
        int lane = t & 63;
        int frag = t >> 6;         // 0..31
        int mc   = frag & 3;
        int ctg  = frag >> 2;
        int att  = ctg * 16 + (lane & 15);
        int m0   = mc * 32 + (lane >> 4) * 8;
        half8 vh, vl;
        #pragma unroll
        for (int j = 0; j < 8; ++j) {
            float v = w1[att * MDIM + m0 + j];
            _Float16 h = (_Float16)v;
            vh[j] = h;
            vl[j] = (_Float16)(v - (float)h);
        }
        *(half8*)(w1h + (size_t)t * 8) = vh;
        *(half8*)(w1l + (size_t)t * 8) = vl;
    }
}

// ---------------------------------------------------------------------------
// Kernel 1: fused x@g (fp16-split MFMA) -> gaussian -> H -> attention (MFMA)
//   grid: N/64 blocks x 512 threads (8 waves).
//   wave w: n-half = w>>2 (32 nodes, rt=2), col-quarter = w&3 (32 cols, ct=2).
//   NOTE: no register double-buffer — R4 showed it spills at this occupancy
//   (FETCH 2 GB of scratch traffic). R3 structure + mu/sigma prefetch +
//   per-k barrier (keeps wave pairs lockstep for L1 B-frag sharing).
// ---------------------------------------------------------------------------
__global__ __launch_bounds__(512, 4) void fused_forward(
    const float* __restrict__ x,
    const _Float16* __restrict__ gh, const _Float16* __restrict__ gl,
    const float* __restrict__ mu, const float* __restrict__ sigma,
    const _Float16* __restrict__ w1h, const _Float16* __restrict__ w1l,
    const float* __restrict__ w2,
    float* __restrict__ Hout, float* __restrict__ scores)
{
    // xs_h/xs_l: [64 nodes][264 f16]  (row stride 528B -> 2-way bank alias, free)
    __shared__ unsigned char smem[64 * 264 * 2 * 2 + 512];   // 68096 B
    _Float16* xs_h = (_Float16*)smem;
    _Float16* xs_l = xs_h + 64 * 264;
    float*    Hs   = (float*)smem;                       // overlay [64][132] f32
    float*    spart = (float*)(smem + 64 * 264 * 2 * 2); // [64][4] att partials

    const int tid   = threadIdx.x;
    const int nBase = blockIdx.x * TSN;

    // ---- stage x tile as fp16 hi/lo ----
    {
        const float4* xg = (const float4*)x;   // 64 float4 per row
        #pragma unroll
        for (int r = 0; r < 8; ++r) {
            int idx  = r * 512 + tid;
            int row  = idx >> 6;       // 0..63
            int quad = idx & 63;       // f-quad
            float4 v = xg[(size_t)(nBase + row) * 64 + quad];
            half4 h, l;
            h[0] = (_Float16)v.x; l[0] = (_Float16)(v.x - (float)h[0]);
            h[1] = (_Float16)v.y; l[1] = (_Float16)(v.y - (float)h[1]);
            h[2] = (_Float16)v.z; l[2] = (_Float16)(v.z - (float)h[2]);
            h[3] = (_Float16)v.w; l[3] = (_Float16)(v.w - (float)h[3]);
            *(half4*)&xs_h[row * 264 + quad * 4] = h;
            *(half4*)&xs_l[row * 264 + quad * 4] = l;
        }
    }
    __syncthreads();

    const int wave  = tid >> 6;
    const int lane  = tid & 63;
    const int c15   = lane & 15;
    const int q     = lane >> 4;
    const int nhalf = wave >> 2;   // 0..1
    const int colq  = wave & 3;    // 0..3

    float h[2][2][4];              // [rt][ct][reg] persistent H accumulator
    #pragma unroll
    for (int rt = 0; rt < 2; ++rt)
        #pragma unroll
        for (int ct = 0; ct < 2; ++ct)
            #pragma unroll
            for (int rg = 0; rg < 4; ++rg) h[rt][ct][rg] = 0.f;

    #pragma unroll 1
    for (int k = 0; k < KMIX; ++k) {
        __syncthreads();   // keep waves lockstep per k: wave pairs share B frags (L1)

        // prefetch mu/sigma for this k (consumed in epilogue, loads hide under MFMAs)
        float muv[2], iv[2];
        #pragma unroll
        for (int ct = 0; ct < 2; ++ct) {
            int col = k * 128 + colq * 32 + ct * 16 + c15;
            muv[ct] = mu[col];
            float sg = sigma[col];
            iv[ct]  = 1.0f / (1e-15f + sg * sg);
        }

        floatx4 acc[2][2];
        #pragma unroll
        for (int rt = 0; rt < 2; ++rt)
            #pragma unroll
            for (int ct = 0; ct < 2; ++ct) acc[rt][ct] = (floatx4)0.f;

        #pragma unroll 2
        for (int fc = 0; fc < 8; ++fc) {
            const int f0 = fc * 32 + q * 8;
            half8 Ah[2], Al[2];
            #pragma unroll
            for (int rt = 0; rt < 2; ++rt) {
                int node = nhalf * 32 + rt * 16 + c15;
                Ah[rt] = *(const half8*)&xs_h[node * 264 + f0];
                Al[rt] = *(const half8*)&xs_l[node * 264 + f0];
            }
            half8 Bh[2], Bl[2];
            #pragma unroll
            for (int ct = 0; ct < 2; ++ct) {
                int ctg = colq * 2 + ct;
                size_t off = ((size_t)((k * 8 + ctg) * 8 + fc) * 64 + lane) * 8;
                Bh[ct] = *(const half8*)(gh + off);
                Bl[ct] = *(const half8*)(gl + off);
            }
            #pragma unroll
            for (int rt = 0; rt < 2; ++rt)
                #pragma unroll
                for (int ct = 0; ct < 2; ++ct) {
                    acc[rt][ct] = __builtin_amdgcn_mfma_f32_16x16x32_f16(Ah[rt], Bh[ct], acc[rt][ct], 0, 0, 0);
                    acc[rt][ct] = __builtin_amdgcn_mfma_f32_16x16x32_f16(Ah[rt], Bl[ct], acc[rt][ct], 0, 0, 0);
                    acc[rt][ct] = __builtin_amdgcn_mfma_f32_16x16x32_f16(Al[rt], Bh[ct], acc[rt][ct], 0, 0, 0);
                }
        }

        // gaussian epilogue: C layout col = lane&15, row = q*4 + reg
        #pragma unroll
        for (int ct = 0; ct < 2; ++ct) {
            #pragma unroll
            for (int rt = 0; rt < 2; ++rt)
                #pragma unroll
                for (int rg = 0; rg < 4; ++rg) {
                    float o = acc[rt][ct][rg];
                    float d = o - muv[ct];
                    h[rt][ct][rg] += o * __expf(-0.5f * d * d * iv[ct]);
                }
        }
    }

    // ---- H -> LDS overlay ----
    __syncthreads();                   // all xs reads done before Hs overlay
    const int HS_LD = MDIM + 4;
    #pragma unroll
    for (int rt = 0; rt < 2; ++rt)
        #pragma unroll
        for (int ct = 0; ct < 2; ++ct)
            #pragma unroll
            for (int rg = 0; rg < 4; ++rg) {
                int n = nhalf * 32 + rt * 16 + q * 4 + rg;
                int m = colq * 32 + ct * 16 + c15;
                Hs[n * HS_LD + m] = h[rt][ct][rg];
            }
    __syncthreads();

    // ---- vectorized, coalesced H store from LDS ----
    #pragma unroll
    for (int r = 0; r < 4; ++r) {
        int idx  = r * 512 + tid;      // 0..2047
        int node = idx >> 5;           // 0..63
        int mq   = idx & 31;           // float4 column
        float4 v = *(const float4*)&Hs[node * HS_LD + mq * 4];
        *(float4*)&Hout[(size_t)(nBase + node) * MDIM + mq * 4] = v;
    }

    // ---- attention via MFMA: dots = H @ w1^T (fp16 split), same wave tiling
    {
        floatx4 datt[2][2];
        #pragma unroll
        for (int rt = 0; rt < 2; ++rt)
            #pragma unroll
            for (int ct = 0; ct < 2; ++ct) datt[rt][ct] = (floatx4)0.f;

        #pragma unroll
        for (int mc = 0; mc < 4; ++mc) {
            half8 Ahh[2], All[2];
            #pragma unroll
            for (int rt = 0; rt < 2; ++rt) {
                int node = nhalf * 32 + rt * 16 + c15;
                const float* hp = &Hs[node * HS_LD + mc * 32 + q * 8];
                #pragma unroll
                for (int j = 0; j < 8; ++j) {
                    float v = hp[j];
                    _Float16 hi = (_Float16)v;
                    Ahh[rt][j] = hi;
                    All[rt][j] = (_Float16)(v - (float)hi);
                }
            }
            #pragma unroll
            for (int ct = 0; ct < 2; ++ct) {
                int frag = (colq * 2 + ct) * 4 + mc;
                size_t off = ((size_t)frag * 64 + lane) * 8;
                half8 Bhh = *(const half8*)(w1h + off);
                half8 Bll = *(const half8*)(w1l + off);
                #pragma unroll
                for (int rt = 0; rt < 2; ++rt) {
                    datt[rt][ct] = __builtin_amdgcn_mfma_f32_16x16x32_f16(Ahh[rt], Bhh, datt[rt][ct], 0, 0, 0);
                    datt[rt][ct] = __builtin_amdgcn_mfma_f32_16x16x32_f16(Ahh[rt], Bll, datt[rt][ct], 0, 0, 0);
                    datt[rt][ct] = __builtin_amdgcn_mfma_f32_16x16x32_f16(All[rt], Bhh, datt[rt][ct], 0, 0, 0);
                }
            }
        }

        // tanh * w2, reduce over wave's 32 atts -> spart[node][colq]
        float w2v[2];
        #pragma unroll
        for (int ct = 0; ct < 2; ++ct) w2v[ct] = w2[colq * 32 + ct * 16 + c15];

        #pragma unroll
        for (int rt = 0; rt < 2; ++rt) {
            #pragma unroll
            for (int rg = 0; rg < 4; ++rg) {
                float p = 0.f;
                #pragma unroll
                for (int ct = 0; ct < 2; ++ct) {
                    float dot = datt[rt][ct][rg];
                    float e2 = __expf(2.f * dot);      // tanh = 1 - 2/(e^2x+1)
                    float av = 1.f - 2.f / (e2 + 1.f);
                    p = fmaf(av, w2v[ct], p);
                }
                p += __shfl_xor(p, 1);
                p += __shfl_xor(p, 2);
                p += __shfl_xor(p, 4);
                p += __shfl_xor(p, 8);
                if (c15 == 0) {
                    int n = nhalf * 32 + rt * 16 + q * 4 + rg;
                    spart[n * 4 + colq] = p;
                }
            }
        }
    }
    __syncthreads();
    if (tid < 64) {
        const float* sp = &spart[tid * 4];
        scores[nBase + tid] = (sp[0] + sp[1]) + (sp[2] + sp[3]);
    }
}

// ---------------------------------------------------------------------------
// Kernel 2: per-graph segment softmax + weighted pooling.
//   2 blocks per graph (m-halves); e staged in LDS; 16-way node parallelism.
// ---------------------------------------------------------------------------
#define CHUNK 1024
__global__ __launch_bounds__(256) void segment_pool(
    const float* __restrict__ H, const float* __restrict__ scores,
    const int* __restrict__ batch, float* __restrict__ out)
{
    const int gidx = blockIdx.x >> 1;
    const int mh   = blockIdx.x & 1;       // m half: 0 -> m 0..63, 1 -> 64..127
    const int tid  = threadIdx.x;

    int lo = 0, hi = N_NODES;
    while (lo < hi) { int mid = (lo + hi) >> 1; if (batch[mid] <  gidx) lo = mid + 1; else hi = mid; }
    const int start = lo;
    hi = N_NODES;
    while (lo < hi) { int mid = (lo + hi) >> 1; if (batch[mid] <= gidx) lo = mid + 1; else hi = mid; }
    const int end = lo;

    __shared__ float red[4];
    __shared__ float ebuf[CHUNK];          // 4KB
    __shared__ float part[16][64];         // 4KB

    // ---- segment max ----
    float mx = -INFINITY;
    for (int i = start + tid; i < end; i += 256) mx = fmaxf(mx, scores[i]);
    #pragma unroll
    for (int o = 32; o > 0; o >>= 1) mx = fmaxf(mx, __shfl_xor(mx, o));
    if ((tid & 63) == 0) red[tid >> 6] = mx;
    __syncthreads();
    mx = fmaxf(fmaxf(red[0], red[1]), fmaxf(red[2], red[3]));
    __syncthreads();                       // red reused for sum below

    // ---- chunked: stage e in LDS, pool with float4 ----
    const int mq = tid & 15;               // float4 column within half (0..15)
    const int p  = tid >> 4;               // node-parallel 0..15
    const float* Hb = H + mh * 64;
    float4 acc = make_float4(0.f, 0.f, 0.f, 0.f);
    float ls = 0.f;                        // local sum of e

    for (int c0 = start; c0 < end; c0 += CHUNK) {
        const int clen = min(end - c0, CHUNK);
        __syncthreads();                   // ebuf reuse from previous chunk
        for (int i = tid; i < clen; i += 256) {
            float e = __expf(scores[c0 + i] - mx);
            ebuf[i] = e;
            ls += e;
        }
        __syncthreads();
        for (int i = p; i < clen; i += 16) {
            float e = ebuf[i];
            const float4 hv = *(const float4*)&Hb[(size_t)(c0 + i) * MDIM + mq * 4];
            acc.x = fmaf(e, hv.x, acc.x);
            acc.y = fmaf(e, hv.y, acc.y);
            acc.z = fmaf(e, hv.z, acc.z);
            acc.w = fmaf(e, hv.w, acc.w);
        }
    }

    // ---- reduce sum of e ----
    #pragma unroll
    for (int o = 32; o > 0; o >>= 1) ls += __shfl_xor(ls, o);
    if ((tid & 63) == 0) red[tid >> 6] = ls;
    // ---- reduce acc over p via LDS ----
    part[p][mq * 4 + 0] = acc.x;
    part[p][mq * 4 + 1] = acc.y;
    part[p][mq * 4 + 2] = acc.z;
    part[p][mq * 4 + 3] = acc.w;
    __syncthreads();
    if (tid < 64) {
        float s = red[0] + red[1] + red[2] + red[3];
        const float inv = 1.f / (s + 1e-16f);
        float a = 0.f;
        #pragma unroll
        for (int pp = 0; pp < 16; ++pp) a += part[pp][tid];
        out[gidx * MDIM + mh * 64 + tid] = a * inv;
    }
}

// ---------------------------------------------------------------------------
extern "C" void kernel_launch(void* const* d_in, const int* in_sizes, int n_in,
                              void* d_out, int out_size, void* d_ws, size_t ws_size,
                              hipStream_t stream)
{
    const float* x     = (const float*)d_in[0];
    const float* g     = (const float*)d_in[1];
    const float* mu    = (const float*)d_in[2];
    const float* sigma = (const float*)d_in[3];
    const float* w1    = (const float*)d_in[4];
    const float* w2    = (const float*)d_in[5];
    const int*   batch = (const int*)d_in[6];
    float* out = (float*)d_out;

    // ws: H [N][128] f32 | scores [N] f32 | gh | gl | w1h | w1l
    float*    H      = (float*)d_ws;
    float*    scores = H + (size_t)N_NODES * MDIM;
    _Float16* ghp    = (_Float16*)(scores + N_NODES);
    _Float16* glp    = ghp + (size_t)FDIM * KMIX * MDIM;
    _Float16* w1hp   = glp + (size_t)FDIM * KMIX * MDIM;
    _Float16* w1lp   = w1hp + (size_t)ATTD * MDIM;

    pack_both<<<136, 256, 0, stream>>>(g, w1, ghp, glp, w1hp, w1lp);
    fused_forward<<<N_NODES / TSN, 512, 0, stream>>>(x, ghp, glp, mu, sigma,
                                                     w1hp, w1lp, w2, H, scores);
    segment_pool<<<NGRAPH * 2, 256, 0, stream>>>(H, scores, batch, out);
}